// Round 10
// baseline (1135.412 us; speedup 1.0000x reference)
//
#include <hip/hip_runtime.h>

#define DEV static __device__ __forceinline__

typedef float f32x4 __attribute__((ext_vector_type(4)));
typedef __bf16 bf16x8 __attribute__((ext_vector_type(8)));
typedef unsigned int u32x4 __attribute__((ext_vector_type(4)));
typedef unsigned int u32x2 __attribute__((ext_vector_type(2)));
typedef unsigned short u16x8 __attribute__((ext_vector_type(8)));

#define NNODE 32768
#define NEDGE 393216
#define EPAD (NEDGE + 16 * NNODE)

DEV unsigned short f2bf(float f) {
    unsigned int u = __builtin_bit_cast(unsigned int, f);
    u += 0x7FFFu + ((u >> 16) & 1u);
    return (unsigned short)(u >> 16);
}
DEV float bf2f(unsigned int b) {
    unsigned int u = b << 16;
    return __builtin_bit_cast(float, u);
}
DEV unsigned int pk2(float a, float b) {
    return (unsigned int)f2bf(a) | ((unsigned int)f2bf(b) << 16);
}
DEV float sigf(float x) { return 1.f / (1.f + __expf(-x)); }

// async global->LDS, 16B per lane; LDS dest = wave-uniform base + lane*16
DEV void gld16(const void* g, void* l) {
    __builtin_amdgcn_global_load_lds(
        (const __attribute__((address_space(1))) void*)(g),
        (__attribute__((address_space(3))) void*)(l),
        16, 0, 0);
}

// ---------------- setup (init + weight packing + CSR pad/count, ONE launch) ---
// blocks [0, NNODE+8): state/feat init + Hmsg zero row.
// blocks [NNODE+8, NNODE+8+6404): weight packing (4 ranges).
// blocks [NNODE+8+6404, +3584): edat dummy-pad + degree count (cnt pre-zeroed).
__global__ __launch_bounds__(256) void setup_k(
    const float* __restrict__ feat,
    unsigned short* __restrict__ hb0, unsigned short* __restrict__ hb1,
    unsigned short* __restrict__ fb, unsigned short* __restrict__ HmsgZ,
    const float* __restrict__ Wm,
    const float* __restrict__ Wi, const float* __restrict__ Wh,
    const float* __restrict__ bi, const float* __restrict__ bh,
    const float* __restrict__ c1w, const float* __restrict__ c2w,
    const float* __restrict__ cc1w, const float* __restrict__ cc2w,
    unsigned short* __restrict__ WT, unsigned short* __restrict__ B2T,
    float* __restrict__ b2,
    unsigned short* __restrict__ BTY, unsigned short* __restrict__ BT2,
    unsigned short* __restrict__ BTZ, unsigned short* __restrict__ BTc2,
    const int* __restrict__ dstv, int* __restrict__ cnt, int* __restrict__ edat)
{
    int blk = blockIdx.x;
    if (blk < NNODE + 8) {
        int idx = blk * 256 + threadIdx.x;
        int r = idx >> 8, c = idx & 255;
        float f = 0.f;
        if (r < NNODE && c < 128) f = feat[(size_t)r * 128 + c];
        unsigned short v = f2bf(f);
        hb0[(size_t)r * 256 + c] = v;
        hb1[(size_t)r * 256 + c] = v;
        if (c < 128) fb[(size_t)r * 128 + c] = v;
        if (r >= NNODE && r < NNODE + 4)
            HmsgZ[(size_t)(r - NNODE) * 256 + c] = 0;
        return;
    }
    if (blk >= NNODE + 8 + 6404) {                          // CSR pad + count
        int e = (blk - (NNODE + 8 + 6404)) * 256 + threadIdx.x;
        edat[e] = NNODE;
        if (e < NEDGE) atomicAdd(&cnt[dstv[e]], 1);
        return;
    }
    int gid = (blk - (NNODE + 8)) * 256 + threadIdx.x;
    if (gid < 262144) {                                     // WT
        int idx = gid;
        int j = idx >> 8, d = idx & 255;
        int t = j >> 8, o = j & 255;
        WT[idx] = f2bf(Wm[t * 65536 + d * 256 + o]);
    } else if (gid < 786432) {                              // B2T
        int idx = gid - 262144;
        int j = idx >> 9, k = idx & 511;
        int band = j >> 6, g = (j >> 4) & 3, ch = (band << 4) + (j & 15);
        float v = 0.f;
        if (g == 0) v = (k < 256) ? Wi[k * 768 + ch] : Wh[(k - 256) * 768 + ch];
        else if (g == 1) v = (k < 256) ? Wi[k * 768 + 256 + ch] : Wh[(k - 256) * 768 + 256 + ch];
        else if (g == 2) { if (k < 256) v = Wi[k * 768 + 512 + ch]; }
        else { if (k >= 256) v = Wh[(k - 256) * 768 + 512 + ch]; }
        B2T[idx] = f2bf(v);
    } else if (gid < 787456) {                              // b2
        int j = gid - 786432;
        int band = j >> 6, g = (j >> 4) & 3, ch = (band << 4) + (j & 15);
        float v;
        if (g == 0) v = bi[ch] + bh[ch];
        else if (g == 1) v = bi[256 + ch] + bh[256 + ch];
        else if (g == 2) v = bi[512 + ch];
        else v = bh[512 + ch];
        b2[j] = v;
    } else {                                                // conv packs
        int idx = gid - 787456;
        if (idx < 196608) {                                 // BTY
            int o = idx / 768, kk = idx - o * 768, k = kk >> 8, c = kk & 255;
            BTY[idx] = f2bf(c1w[o * 768 + c * 3 + k]);
        } else if (idx < 262144) {                          // BT2 [o][c]
            int r = idx - 196608, o = r >> 8, c = r & 255;
            BT2[r] = f2bf(c2w[o * 256 + c]);
        } else if (idx < 704512) {                          // BTZ
            int jx = idx - 262144, o = jx / 1152, kk = jx - o * 1152;
            float v;
            if (kk < 768) { int k = kk >> 8, c = kk & 255; v = cc1w[o * 1152 + c * 3 + k]; }
            else { int r = kk - 768, kf = r >> 7, cf = r & 127; v = cc1w[o * 1152 + (256 + cf) * 3 + kf]; }
            BTZ[jx] = f2bf(v);
        } else {                                            // BTc2 [o][c]
            int r = idx - 704512, o = r / 384, c = r - o * 384;
            BTc2[r] = f2bf(cc2w[o * 384 + c]);
        }
    }
}

// ---------------- CSR build (segments padded to multiple of 16) ----------------

// shfl-based hierarchical scan over PADDED counts ((cnt+15)&~15):
// per-wave inclusive scan -> 16 wave-sums scanned by wave 0 -> offset add.
// 2 barriers (was 20). Block offsets applied at READ time via boff.
__global__ __launch_bounds__(1024) void scan1_k(
    const int* __restrict__ cnt, int* __restrict__ rp, int* __restrict__ bsum)
{
    __shared__ int wsum[16];
    __shared__ int woff[16];
    int b = blockIdx.x, tid = threadIdx.x;
    int wave = tid >> 6, lane = tid & 63;
    int n = (b << 10) + tid;
    int v = (cnt[n] + 15) & ~15;            // padded segment length
    int s = v;
    #pragma unroll
    for (int off = 1; off < 64; off <<= 1) {
        int x = __shfl_up(s, off, 64);
        if (lane >= off) s += x;
    }
    if (lane == 63) wsum[wave] = s;
    __syncthreads();
    if (wave == 0) {
        int t = (lane < 16) ? wsum[lane] : 0;
        int ss = t;
        #pragma unroll
        for (int off = 1; off < 16; off <<= 1) {
            int x = __shfl_up(ss, off, 64);
            if (lane >= off) ss += x;
        }
        if (lane < 16) woff[lane] = ss - t; // exclusive wave offset
        if (lane == 15) bsum[b] = ss;       // block total
    }
    __syncthreads();
    rp[n] = s - v + woff[wave];             // local exclusive
}

__global__ __launch_bounds__(64) void scan2_k(
    const int* __restrict__ bsum, int* __restrict__ boff, int* __restrict__ rp)
{
    int lane = threadIdx.x;
    int v = (lane < 32) ? bsum[lane] : 0;
    int s = v;
    #pragma unroll
    for (int off = 1; off < 32; off <<= 1) {
        int x = __shfl_up(s, off, 64);
        if (lane >= off) s += x;
    }
    if (lane < 32) boff[lane] = s - v;      // exclusive block offset
    if (lane == 32) boff[32] = 0;           // sentinel for n+1 == NNODE
    if (lane == 31) rp[NNODE] = s;          // grand total (padded, full value)
}

__global__ __launch_bounds__(256) void fill_k(
    const int* __restrict__ src, const int* __restrict__ dst,
    const int* __restrict__ et, const int* __restrict__ rp,
    const int* __restrict__ boff,
    int* __restrict__ pos, int* __restrict__ edat)
{
    int e = blockIdx.x * 256 + threadIdx.x;
    int d = dst[e];
    int p = atomicAdd(&pos[d], 1);
    edat[rp[d] + boff[d >> 10] + p] = src[e] | (et[e] << 20);
}

// ---------------- per-step kernels ----------------

// one wave per node: gather Hmsg[src, et*256 .. +256] rows, sum fp32 -> Aonly.
// 16B/lane loads (32 lanes span a row), 2 edges in flight across lane halves,
// segments padded to x16 (dummy -> zero row). shfl_xor(32) combines halves.
// XCD-chunk swizzle: each XCD gets 1024 contiguous blocks (= 16 graphs) so
// a graph's Hmsg slice stays in one XCD's L2 (~3x edge reuse -> L2 hits).
__global__ __launch_bounds__(256) void agg2_k(
    const int* __restrict__ rp, const int* __restrict__ boff,
    const int* __restrict__ edat,
    const unsigned short* __restrict__ Hmsg, unsigned short* __restrict__ Aonly)
{
    int wave = threadIdx.x >> 6, lane = threadIdx.x & 63;
    int id = blockIdx.x;                    // 8192
    { id = (id & 7) * (gridDim.x >> 3) + (id >> 3); }
    int n = (id << 2) + wave;
    int e0 = rp[n] + boff[n >> 10];
    int e1 = rp[n + 1] + boff[(n + 1) >> 10];
    int half = lane >> 5, lc = lane & 31;
    float a0 = 0.f, a1 = 0.f, a2 = 0.f, a3 = 0.f;
    float a4 = 0.f, a5 = 0.f, a6 = 0.f, a7 = 0.f;
    const unsigned short* hc = Hmsg + (lc << 3);
    for (int e = e0; e < e1; e += 16) {
        u32x4 v[8];
        #pragma unroll
        for (int q = 0; q < 8; q++) {
            int d = edat[e + (q << 1) + half];
            v[q] = *(const u32x4*)(hc + ((size_t)(d & 0xFFFFF) << 10) + ((d >> 20) << 8));
        }
        #pragma unroll
        for (int q = 0; q < 8; q++) {
            a0 += bf2f(v[q].x & 0xFFFFu); a1 += bf2f(v[q].x >> 16);
            a2 += bf2f(v[q].y & 0xFFFFu); a3 += bf2f(v[q].y >> 16);
            a4 += bf2f(v[q].z & 0xFFFFu); a5 += bf2f(v[q].z >> 16);
            a6 += bf2f(v[q].w & 0xFFFFu); a7 += bf2f(v[q].w >> 16);
        }
    }
    a0 += __shfl_xor(a0, 32, 64); a1 += __shfl_xor(a1, 32, 64);
    a2 += __shfl_xor(a2, 32, 64); a3 += __shfl_xor(a3, 32, 64);
    a4 += __shfl_xor(a4, 32, 64); a5 += __shfl_xor(a5, 32, 64);
    a6 += __shfl_xor(a6, 32, 64); a7 += __shfl_xor(a7, 32, 64);
    if (half == 0) {
        u32x4 p;
        p.x = pk2(a0, a1); p.y = pk2(a2, a3);
        p.z = pk2(a4, a5); p.w = pk2(a6, a7);
        *(u32x4*)(Aonly + (size_t)n * 256 + (lc << 3)) = p;
    }
}

// ---- BK=64 staging helpers, bank-conflict-free XOR swizzle.
#define STAGE_COORDS                                            \
    int srow[4], scb[4], soff[4];                               \
    _Pragma("unroll")                                           \
    for (int p = 0; p < 4; p++) {                               \
        int c = wave + p * 4;                                   \
        int half = c >> 3, cc = c & 7;                          \
        srow[p] = cc * 16 + (lane >> 2);                        \
        scb[p] = (((lane & 3) ^ ((lane >> 3) & 3)) + half * 4) * 8; \
        soff[p] = half * 4096 + cc * 512;                       \
    }

// MFMA over one 64-K LDS tile pair (two 32-K halves), swapped operands,
// swizzled fragment reads
#define MFMA64(AS, BS)                                                        \
    _Pragma("unroll")                                                         \
    for (int h = 0; h < 2; h++) {                                             \
        bf16x8 af[4], bfr[4];                                                 \
        _Pragma("unroll")                                                     \
        for (int i = 0; i < 4; i++)                                           \
            af[i] = *(const bf16x8*)(&(AS)[h * 4096 + (qm + i * 16 + fm) * 32 + fksw * 8]); \
        _Pragma("unroll")                                                     \
        for (int i = 0; i < 4; i++)                                           \
            bfr[i] = *(const bf16x8*)(&(BS)[h * 4096 + (qn + i * 16 + fm) * 32 + fksw * 8]); \
        _Pragma("unroll")                                                     \
        for (int i = 0; i < 4; i++)                                           \
            _Pragma("unroll")                                                 \
            for (int j = 0; j < 4; j++)                                       \
                acc[i][j] = __builtin_amdgcn_mfma_f32_16x16x32_bf16(bfr[j], af[i], acc[i][j], 0, 0, 0); \
    }

// gate-skip variant: skip j-fragment SK (its B2T block is exactly zero)
#define MFMA64G(AS, BS, SK)                                                   \
    _Pragma("unroll")                                                         \
    for (int h = 0; h < 2; h++) {                                             \
        bf16x8 af[4], bfr[4];                                                 \
        _Pragma("unroll")                                                     \
        for (int i = 0; i < 4; i++)                                           \
            af[i] = *(const bf16x8*)(&(AS)[h * 4096 + (qm + i * 16 + fm) * 32 + fksw * 8]); \
        _Pragma("unroll")                                                     \
        for (int j = 0; j < 4; j++) {                                         \
            if (j == (SK)) continue;                                          \
            bfr[j] = *(const bf16x8*)(&(BS)[h * 4096 + (qn + j * 16 + fm) * 32 + fksw * 8]); \
        }                                                                     \
        _Pragma("unroll")                                                     \
        for (int i = 0; i < 4; i++)                                           \
            _Pragma("unroll")                                                 \
            for (int j = 0; j < 4; j++) {                                     \
                if (j == (SK)) continue;                                      \
                acc[i][j] = __builtin_amdgcn_mfma_f32_16x16x32_bf16(bfr[j], af[i], acc[i][j], 0, 0, 0); \
            }                                                                 \
    }

// Hmsg GEMM: C[Nn,1024] = h @ WT^T + bmsg. 128x128 tile, BK=64, K=NT*64,
// 2-phase dbuf staging, XCD swizzle. NT=2 at step 0 (h cols 128..255 zero).
template<int NT>
__global__ __launch_bounds__(256) void gemm_hmsg(
    const unsigned short* __restrict__ A,
    const unsigned short* __restrict__ Bt,
    unsigned short* __restrict__ Cb,
    const float* __restrict__ bias)
{
    __shared__ __align__(16) unsigned short As0[128 * 64];
    __shared__ __align__(16) unsigned short As1[128 * 64];
    __shared__ __align__(16) unsigned short Bs0[128 * 64];
    __shared__ __align__(16) unsigned short Bs1[128 * 64];
    const int tid = threadIdx.x;
    int id = blockIdx.x;                        // 2048
    { int per = gridDim.x >> 3; id = (id & 7) * per + (id >> 3); }
    const int bm = id >> 3, bn = id & 7;
    const int wave = tid >> 6, lane = tid & 63;
    const unsigned short* Ag = A + (size_t)(bm * 128) * 256;
    const unsigned short* Bg = Bt + (size_t)(bn * 128) * 256;
    const int qm = (wave & 1) << 6, qn = (wave >> 1) << 6;
    const int fm = lane & 15, fkv = lane >> 4;
    const int fksw = fkv ^ ((fm >> 1) & 3);
    STAGE_COORDS

    auto stageA = [&](int kb, unsigned short* dst) {
        #pragma unroll
        for (int p = 0; p < 4; p++)
            gld16(Ag + (size_t)srow[p] * 256 + kb + scb[p], dst + soff[p]);
    };
    auto stageB = [&](int kb, unsigned short* dst) {
        #pragma unroll
        for (int p = 0; p < 4; p++)
            gld16(Bg + (size_t)srow[p] * 256 + kb + scb[p], dst + soff[p]);
    };

    f32x4 acc[4][4] = {};

    stageA(0, As0); stageB(0, Bs0);
    __syncthreads();
    unsigned short *Ac = As0, *An = As1, *Bc = Bs0, *Bn = Bs1;
    #pragma unroll
    for (int kb = 0; kb < NT * 64; kb += 64) {
        if (kb + 64 < NT * 64) { stageA(kb + 64, An); stageB(kb + 64, Bn); }
        MFMA64(Ac, Bc)
        __syncthreads();
        { auto t = Ac; Ac = An; An = t; }
        { auto t = Bc; Bc = Bn; Bn = t; }
    }

    const int m0 = bm * 128 + qm + fm;
    const int n0 = bn * 128 + qn + (fkv << 2);
    #pragma unroll
    for (int i = 0; i < 4; i++) {
        int row = m0 + i * 16;
        #pragma unroll
        for (int j = 0; j < 4; j++) {
            int col = n0 + j * 16;
            float4 bv = *(const float4*)(bias + col);
            u32x2 p;
            p.x = pk2(acc[i][j][0] + bv.x, acc[i][j][1] + bv.y);
            p.y = pk2(acc[i][j][2] + bv.z, acc[i][j][3] + bv.w);
            *(u32x2*)(Cb + (size_t)row * 1024 + col) = p;
        }
    }
}

// merged conv1 GEMMs (Y then Z) in ONE launch; blocks [0,512) = Y
// (N=256,K=768), [512,1280) = Z (N=384,K=1152). Per-segment XCD swizzle.
// K layout: kb<768 -> h chunks (lda 256, shift kb>>8), kb>=768 -> f chunks
// (lda 128, shift (kb-768)>>7). BK=64. 2-phase dbuf staging.
__global__ __launch_bounds__(256) void gemm_conv2(
    const unsigned short* __restrict__ Ah,
    const unsigned short* __restrict__ Af,
    const unsigned short* __restrict__ BtY,
    const unsigned short* __restrict__ BtZ,
    unsigned short* __restrict__ CbYo,
    unsigned short* __restrict__ CbZo,
    const float* __restrict__ biasY,
    const float* __restrict__ biasZ)
{
    __shared__ __align__(16) unsigned short As0[128 * 64];
    __shared__ __align__(16) unsigned short As1[128 * 64];
    __shared__ __align__(16) unsigned short Bs0[128 * 64];
    __shared__ __align__(16) unsigned short Bs1[128 * 64];
    const int tid = threadIdx.x;
    const unsigned short* Bt; unsigned short* Cb;
    const float* bias; int N, K, ldcb, id;
    if (blockIdx.x < 512) {
        id = blockIdx.x;
        { int per = 512 >> 3; id = (id & 7) * per + (id >> 3); }
        Bt = BtY; Cb = CbYo; bias = biasY; N = 256; K = 768; ldcb = 256;
    } else {
        id = blockIdx.x - 512;
        { int per = 768 >> 3; id = (id & 7) * per + (id >> 3); }
        Bt = BtZ; Cb = CbZo; bias = biasZ; N = 384; K = 1152; ldcb = 384;
    }
    const int nb = N >> 7;
    const int bm = id / nb, bn = id - bm * nb;
    const int wave = tid >> 6, lane = tid & 63;
    const unsigned short* Bg = Bt + (size_t)(bn * 128) * K;
    const int qm = (wave & 1) << 6, qn = (wave >> 1) << 6;
    const int fm = lane & 15, fkv = lane >> 4;
    const int fksw = fkv ^ ((fm >> 1) & 3);
    STAGE_COORDS

    auto stageA = [&](int kb, unsigned short* dst) {
        const unsigned short* base; int ldA, col, shift;
        if (kb < 768) { base = Ah; ldA = 256; shift = kb >> 8; col = kb & 255; }
        else { int r = kb - 768; base = Af; ldA = 128; shift = r >> 7; col = r & 127; }
        const unsigned short* Ag = base + (size_t)(bm * 128 + shift) * ldA + col;
        #pragma unroll
        for (int p = 0; p < 4; p++)
            gld16(Ag + (size_t)srow[p] * ldA + scb[p], dst + soff[p]);
    };
    auto stageB = [&](int kb, unsigned short* dst) {
        #pragma unroll
        for (int p = 0; p < 4; p++)
            gld16(Bg + (size_t)srow[p] * K + kb + scb[p], dst + soff[p]);
    };

    f32x4 acc[4][4] = {};

    stageA(0, As0); stageB(0, Bs0);
    __syncthreads();
    unsigned short *Ac = As0, *An = As1, *Bc = Bs0, *Bn = Bs1;
    for (int kb = 0; kb < K; kb += 64) {
        if (kb + 64 < K) { stageA(kb + 64, An); stageB(kb + 64, Bn); }
        MFMA64(Ac, Bc)
        __syncthreads();
        { auto t = Ac; Ac = An; An = t; }
        { auto t = Bc; Bc = Bn; Bn = t; }
    }

    const int m0 = bm * 128 + qm + fm;
    const int n0 = bn * 128 + qn + (fkv << 2);
    #pragma unroll
    for (int i = 0; i < 4; i++) {
        int row = m0 + i * 16;
        #pragma unroll
        for (int j = 0; j < 4; j++) {
            int col = n0 + j * 16;
            float4 bv = *(const float4*)(bias + col);
            float v0 = fmaxf(acc[i][j][0] + bv.x, 0.f);
            float v1 = fmaxf(acc[i][j][1] + bv.y, 0.f);
            float v2 = fmaxf(acc[i][j][2] + bv.z, 0.f);
            float v3 = fmaxf(acc[i][j][3] + bv.w, 0.f);
            u32x2 p; p.x = pk2(v0, v1); p.y = pk2(v2, v3);
            *(u32x2*)(Cb + (size_t)row * ldcb + col) = p;
        }
    }
}

// merged conv2 GEMMs with FUSED maxpool(win3,stride2) on A, ONE launch:
// blocks [0,252) = Y (C=256), [252,630) = Z (C=384). A[row] = max of 3
// consecutive-l rows of CbX (post-relu bf16 -> u16 max is exact).
// Reg-staged A (T14 split: loads before MFMA, max+ds_write after); B gld16.
__global__ __launch_bounds__(256) void gemm_pool2(
    const unsigned short* __restrict__ CbYi,
    const unsigned short* __restrict__ CbZi,
    const unsigned short* __restrict__ BtY,
    const unsigned short* __restrict__ BtZ,
    unsigned short* __restrict__ Cb2Yo,
    unsigned short* __restrict__ Cb2Zo,
    const float* __restrict__ biasY,
    const float* __restrict__ biasZ)
{
    __shared__ __align__(16) unsigned short As0[128 * 64];
    __shared__ __align__(16) unsigned short As1[128 * 64];
    __shared__ __align__(16) unsigned short Bs0[128 * 64];
    __shared__ __align__(16) unsigned short Bs1[128 * 64];
    const int tid = threadIdx.x;
    const unsigned short* CbX; const unsigned short* Bt; unsigned short* Cb;
    const float* bias; int N, K, id;
    if (blockIdx.x < 252) {
        id = blockIdx.x;
        CbX = CbYi; Bt = BtY; Cb = Cb2Yo; bias = biasY; N = 256; K = 256;
    } else {
        id = blockIdx.x - 252;
        CbX = CbZi; Bt = BtZ; Cb = Cb2Zo; bias = biasZ; N = 384; K = 384;
    }
    const int ldin = K, ldcb = N;
    const int nb = N >> 7;
    const int bm = id / nb, bn = id - bm * nb;
    const int wave = tid >> 6, lane = tid & 63;
    const unsigned short* Bg = Bt + (size_t)(bn * 128) * K;
    const int qm = (wave & 1) << 6, qn = (wave >> 1) << 6;
    const int fm = lane & 15, fkv = lane >> 4;
    const int fksw = fkv ^ ((fm >> 1) & 3);
    STAGE_COORDS

    // pooled row -> source row0 in CbX (graph b: 126 pooled rows, 256 src)
    int row0[4];
    #pragma unroll
    for (int p = 0; p < 4; p++) {
        int arow = bm * 128 + srow[p];
        int b = arow / 126, lp = arow - b * 126;
        row0[p] = b * 256 + 2 * lp;
    }

    u16x8 va[4][3];
    auto loadA3 = [&](int kb) {
        #pragma unroll
        for (int p = 0; p < 4; p++) {
            const unsigned short* s = CbX + (size_t)row0[p] * ldin + kb + scb[p];
            va[p][0] = *(const u16x8*)s;
            va[p][1] = *(const u16x8*)(s + ldin);
            va[p][2] = *(const u16x8*)(s + 2 * ldin);
        }
    };
    auto writeA = [&](unsigned short* dst) {
        #pragma unroll
        for (int p = 0; p < 4; p++) {
            u16x8 m = __builtin_elementwise_max(
                __builtin_elementwise_max(va[p][0], va[p][1]), va[p][2]);
            *(u16x8*)(dst + soff[p] + lane * 8) = m;   // same layout as gld16
        }
    };
    auto stageB = [&](int kb, unsigned short* dst) {
        #pragma unroll
        for (int p = 0; p < 4; p++)
            gld16(Bg + (size_t)srow[p] * K + kb + scb[p], dst + soff[p]);
    };

    f32x4 acc[4][4] = {};

    loadA3(0); writeA(As0); stageB(0, Bs0);
    __syncthreads();
    unsigned short *Ac = As0, *An = As1, *Bc = Bs0, *Bn = Bs1;
    for (int kb = 0; kb < K; kb += 64) {
        bool more = (kb + 64 < K);
        if (more) { loadA3(kb + 64); stageB(kb + 64, Bn); }
        MFMA64(Ac, Bc)
        if (more) writeA(An);       // loads' latency hidden under the MFMAs
        __syncthreads();
        { auto t = Ac; Ac = An; An = t; }
        { auto t = Bc; Bc = Bn; Bn = t; }
    }

    const int m0 = bm * 128 + qm + fm;
    const int n0 = bn * 128 + qn + (fkv << 2);
    #pragma unroll
    for (int i = 0; i < 4; i++) {
        int row = m0 + i * 16;
        #pragma unroll
        for (int j = 0; j < 4; j++) {
            int col = n0 + j * 16;
            float4 bv = *(const float4*)(bias + col);
            float v0 = fmaxf(acc[i][j][0] + bv.x, 0.f);
            float v1 = fmaxf(acc[i][j][1] + bv.y, 0.f);
            float v2 = fmaxf(acc[i][j][2] + bv.z, 0.f);
            float v3 = fmaxf(acc[i][j][3] + bv.w, 0.f);
            u32x2 p; p.x = pk2(v0, v1); p.y = pk2(v2, v3);
            *(u32x2*)(Cb + (size_t)row * ldcb + col) = p;
        }
    }
}

// GRU GEMM + fused gate epilogue (swapped MFMA, BK=64, K=NT*64, 2-phase
// dbuf staging, gate-skip). NT=6 at step 0 (h cols 128..255 exactly zero).
template<int NT>
__global__ __launch_bounds__(256) void gemm_gru(
    const unsigned short* __restrict__ Aonly,
    const unsigned short* __restrict__ hbc,
    const unsigned short* __restrict__ Bt,
    const float* __restrict__ b2p,
    unsigned short* __restrict__ hbn)
{
    __shared__ __align__(16) unsigned short As0[128 * 64];
    __shared__ __align__(16) unsigned short As1[128 * 64];
    __shared__ __align__(16) unsigned short Bs0[128 * 64];
    __shared__ __align__(16) unsigned short Bs1[128 * 64];
    const int tid = threadIdx.x;
    int id = blockIdx.x;                        // 2048
    { int per = gridDim.x >> 3; id = (id & 7) * per + (id >> 3); }
    const int bm = id >> 3;
    const int bn = id & 7;
    const int wave = tid >> 6, lane = tid & 63;
    const unsigned short* Bg = Bt + (size_t)(bn * 128) * 512;
    const int qm = (wave & 1) << 6, qn = (wave >> 1) << 6;
    const int fm = lane & 15, fkv = lane >> 4;
    const int fksw = fkv ^ ((fm >> 1) & 3);
    STAGE_COORDS

    auto stageA = [&](int kb, unsigned short* dst) {
        const unsigned short* base = (kb < 256) ? Aonly : hbc;
        const unsigned short* Ag = base + (size_t)(bm * 128) * 256 + (kb & 255);
        #pragma unroll
        for (int p = 0; p < 4; p++)
            gld16(Ag + (size_t)srow[p] * 256 + scb[p], dst + soff[p]);
    };
    auto stageB = [&](int kb, unsigned short* dst) {
        #pragma unroll
        for (int p = 0; p < 4; p++)
            gld16(Bg + (size_t)srow[p] * 512 + kb + scb[p], dst + soff[p]);
    };

    f32x4 acc[4][4] = {};

    stageA(0, As0); stageB(0, Bs0);
    __syncthreads();
    unsigned short *Ac = As0, *An = As1, *Bc = Bs0, *Bn = Bs1;
    #pragma unroll
    for (int kb = 0; kb < NT * 64; kb += 64) {
        if (kb + 64 < NT * 64) { stageA(kb + 64, An); stageB(kb + 64, Bn); }
        if (kb < 256) { MFMA64G(Ac, Bc, 3) }    // hg block zero for k<256
        else          { MFMA64G(Ac, Bc, 2) }    // ig block zero for k>=256
        __syncthreads();
        { auto t = Ac; Ac = An; An = t; }
        { auto t = Bc; Bc = Bn; Bn = t; }
    }

    // fused GRU gate epilogue (bf16 state, 8B vector I/O)
    const int band = (bn << 1) + (qn >> 6);
    const int chb = (band << 4) + (fkv << 2);
    const float4 brv = *(const float4*)(b2p + (band << 6) + 0  + (fkv << 2));
    const float4 bzv = *(const float4*)(b2p + (band << 6) + 16 + (fkv << 2));
    const float4 bgv = *(const float4*)(b2p + (band << 6) + 32 + (fkv << 2));
    const float4 bhv = *(const float4*)(b2p + (band << 6) + 48 + (fkv << 2));
    const float br_[4] = {brv.x, brv.y, brv.z, brv.w};
    const float bz_[4] = {bzv.x, bzv.y, bzv.z, bzv.w};
    const float bg_[4] = {bgv.x, bgv.y, bgv.z, bgv.w};
    const float bh_[4] = {bhv.x, bhv.y, bhv.z, bhv.w};
    const int m0 = bm * 128 + qm + fm;
    #pragma unroll
    for (int i = 0; i < 4; i++) {
        int row = m0 + i * 16;
        u32x2 hv = *(const u32x2*)(hbc + (size_t)row * 256 + chb);
        float hp[4] = {bf2f(hv.x & 0xFFFFu), bf2f(hv.x >> 16),
                       bf2f(hv.y & 0xFFFFu), bf2f(hv.y >> 16)};
        float hn[4];
        #pragma unroll
        for (int r = 0; r < 4; r++) {
            float rg = sigf(acc[i][0][r] + br_[r]);
            float zz = sigf(acc[i][1][r] + bz_[r]);
            float pre = acc[i][2][r] + bg_[r] + rg * (acc[i][3][r] + bh_[r]);
            pre = fminf(fmaxf(pre, -15.f), 15.f);
            float t = __expf(2.f * pre);
            float gq = (t - 1.f) / (t + 1.f);
            hn[r] = (1.f - zz) * gq + zz * hp[r];
        }
        u32x2 p; p.x = pk2(hn[0], hn[1]); p.y = pk2(hn[2], hn[3]);
        *(u32x2*)(hbn + (size_t)row * 256 + chb) = p;
    }
}

// fused pool2(win=2) + dot + mean + sigmoid. 256 threads/graph:
// 4 waves split the 63 l-positions; lanes split channels; shfl reduce.
__global__ __launch_bounds__(256) void final_k(
    const unsigned short* __restrict__ CY, const unsigned short* __restrict__ CZ,
    const float* __restrict__ wy, const float* __restrict__ by,
    const float* __restrict__ wz, const float* __restrict__ bz,
    float* __restrict__ out)
{
    __shared__ float ws[4];
    int b = blockIdx.x, tid = threadIdx.x;
    int wave = tid >> 6, lane = tid & 63;
    float wyv[4], wzv[6];
    #pragma unroll
    for (int j = 0; j < 4; j++) wyv[j] = wy[lane * 4 + j];
    #pragma unroll
    for (int j = 0; j < 6; j++) wzv[j] = wz[lane * 6 + j];
    const float byv = by[0], bzv = bz[0];
    float acc = 0.f;
    for (int l = wave; l < 63; l += 4) {
        const unsigned short* y0 = CY + (size_t)(b * 126 + 2 * l) * 256 + lane * 4;
        const unsigned short* y1 = y0 + 256;
        u32x2 u0 = *(const u32x2*)y0, u1 = *(const u32x2*)y1;
        float py =
            fmaxf(bf2f(u0.x & 0xFFFFu), bf2f(u1.x & 0xFFFFu)) * wyv[0] +
            fmaxf(bf2f(u0.x >> 16),     bf2f(u1.x >> 16))     * wyv[1] +
            fmaxf(bf2f(u0.y & 0xFFFFu), bf2f(u1.y & 0xFFFFu)) * wyv[2] +
            fmaxf(bf2f(u0.y >> 16),     bf2f(u1.y >> 16))     * wyv[3];
        const unsigned short* z0 = CZ + (size_t)(b * 126 + 2 * l) * 384 + lane * 6;
        const unsigned short* z1 = z0 + 384;
        float pz = 0.f;
        #pragma unroll
        for (int j = 0; j < 6; j++)
            pz += fmaxf(bf2f(z0[j]), bf2f(z1[j])) * wzv[j];
        #pragma unroll
        for (int off = 32; off > 0; off >>= 1) {
            py += __shfl_down(py, off, 64);
            pz += __shfl_down(pz, off, 64);
        }
        if (lane == 0) acc += (py + byv) * (pz + bzv);
    }
    if (lane == 0) ws[wave] = acc;
    __syncthreads();
    if (tid == 0)
        out[b] = sigf((ws[0] + ws[1] + ws[2] + ws[3]) * (1.f / 63.f));
}

// ---------------- launch ----------------

extern "C" void kernel_launch(void* const* d_in, const int* in_sizes, int n_in,
                              void* d_out, int out_size, void* d_ws, size_t ws_size,
                              hipStream_t stream)
{
    const float* feat = (const float*)d_in[0];
    const int* src = (const int*)d_in[1];
    const int* dst = (const int*)d_in[2];
    const int* et  = (const int*)d_in[3];
    const float* Wm  = (const float*)d_in[4];
    const float* bm  = (const float*)d_in[5];
    const float* Wi  = (const float*)d_in[6];
    const float* Wh  = (const float*)d_in[7];
    const float* bi  = (const float*)d_in[8];
    const float* bh  = (const float*)d_in[9];
    const float* c1w = (const float*)d_in[10];
    const float* c1b = (const float*)d_in[11];
    const float* c2w = (const float*)d_in[12];
    const float* c2b = (const float*)d_in[13];
    const float* cc1w = (const float*)d_in[14];
    const float* cc1b = (const float*)d_in[15];
    const float* cc2w = (const float*)d_in[16];
    const float* cc2b = (const float*)d_in[17];
    const float* wy = (const float*)d_in[18];
    const float* by = (const float*)d_in[19];
    const float* wz = (const float*)d_in[20];
    const float* bz = (const float*)d_in[21];
    float* out = (float*)d_out;

    char* w = (char*)d_ws;
    size_t off = 0;
    auto alloc = [&](size_t bytes) -> char* {
        char* p = w + off; off += (bytes + 255) & ~(size_t)255; return p;
    };
    unsigned short* hb0 = (unsigned short*)alloc((size_t)(NNODE + 8) * 256 * 2);
    unsigned short* hb1 = (unsigned short*)alloc((size_t)(NNODE + 8) * 256 * 2);
    unsigned short* fb  = (unsigned short*)alloc((size_t)(NNODE + 8) * 128 * 2);
    unsigned short* Aonly = (unsigned short*)alloc((size_t)NNODE * 256 * 2);
    char* R = alloc((size_t)(NNODE + 1) * 1024 * 2);    // Hmsg(+zero row) / conv1-out
    unsigned short* Hmsg = (unsigned short*)R;          // [Nn+1,1024] bf16
    unsigned short* CbY  = (unsigned short*)R;          // [Nn,256] bf16 (conv1 Y)
    unsigned short* CbZ  = (unsigned short*)(R + (size_t)NNODE * 256 * 2); // [Nn,384]
    unsigned short* Cb2Y = (unsigned short*)alloc((size_t)16128 * 256 * 2);
    unsigned short* Cb2Z = (unsigned short*)alloc((size_t)16128 * 384 * 2);
    unsigned short* WT   = (unsigned short*)alloc(1024 * 256 * 2);
    unsigned short* B2T  = (unsigned short*)alloc(1024 * 512 * 2);
    float* b2            = (float*)alloc(1024 * 4);
    unsigned short* BTY  = (unsigned short*)alloc(256 * 768 * 2);
    unsigned short* BT2  = (unsigned short*)alloc(256 * 256 * 2);
    unsigned short* BTZ  = (unsigned short*)alloc(384 * 1152 * 2);
    unsigned short* BTc2 = (unsigned short*)alloc(384 * 384 * 2);
    int* rp     = (int*)alloc((NNODE + 1) * 4);
    int* pos    = (int*)alloc(NNODE * 4);
    int* cnt    = (int*)alloc(NNODE * 4);
    int* bsum   = (int*)alloc(32 * 4);
    int* boff   = (int*)alloc(33 * 4);
    int* edat   = (int*)alloc((size_t)EPAD * 4);

    // setup: memset first (cnt zeroed before setup_k's count range runs)
    hipMemsetAsync(pos, 0, 2 * NNODE * 4, stream);      // pos+cnt contiguous
    hipLaunchKernelGGL(setup_k, dim3(NNODE + 8 + 6404 + EPAD / 256), dim3(256),
                       0, stream,
                       feat, hb0, hb1, fb, Hmsg + (size_t)NNODE * 1024,
                       Wm, Wi, Wh, bi, bh, c1w, c2w, cc1w, cc2w,
                       WT, B2T, b2, BTY, BT2, BTZ, BTc2,
                       dst, cnt, edat);
    hipLaunchKernelGGL(scan1_k, dim3(32), dim3(1024), 0, stream, cnt, rp, bsum);
    hipLaunchKernelGGL(scan2_k, dim3(1), dim3(64), 0, stream, bsum, boff, rp);
    hipLaunchKernelGGL(fill_k, dim3(NEDGE / 256), dim3(256), 0, stream,
                       src, dst, et, rp, boff, pos, edat);

    // 8 GGNN steps; bf16 state double-buffered (hb0 -> hb1 -> hb0 ...)
    // per step: Hmsg = hb@WT + bm  ->  Aonly[dst] = sum Hmsg[src, et]  ->  GRU
    // step 0: h cols 128..255 are exactly zero -> half-K Hmsg, 6-tile GRU.
    unsigned short* hbuf[2] = {hb0, hb1};
    for (int step = 0; step < 8; step++) {
        unsigned short* cur = hbuf[step & 1];
        unsigned short* nxt = hbuf[(step + 1) & 1];
        if (step == 0)
            hipLaunchKernelGGL((gemm_hmsg<2>), dim3(2048), dim3(256), 0, stream,
                cur, WT, Hmsg, bm);
        else
            hipLaunchKernelGGL((gemm_hmsg<4>), dim3(2048), dim3(256), 0, stream,
                cur, WT, Hmsg, bm);
        hipLaunchKernelGGL(agg2_k, dim3(NNODE / 4), dim3(256), 0, stream,
            rp, boff, edat, Hmsg, Aonly);
        if (step == 0)
            hipLaunchKernelGGL((gemm_gru<6>), dim3(2048), dim3(256), 0, stream,
                Aonly, cur, B2T, b2, nxt);
        else
            hipLaunchKernelGGL((gemm_gru<8>), dim3(2048), dim3(256), 0, stream,
                Aonly, cur, B2T, b2, nxt);
    }
    // final state is in hb0 (after 8 flips)

    // readout: merged conv1 (Y+Z, one launch), merged pooled conv2 (Y+Z)
    hipLaunchKernelGGL(gemm_conv2, dim3(1280), dim3(256), 0, stream,
        hb0, fb, BTY, BTZ, CbY, CbZ, c1b, cc1b);
    hipLaunchKernelGGL(gemm_pool2, dim3(630), dim3(256), 0, stream,
        CbY, CbZ, BT2, BTc2, Cb2Y, Cb2Z, c2b, cc2b);

    // fused pool2 + readout heads
    hipLaunchKernelGGL(final_k, dim3(128), dim3(256), 0, stream,
        Cb2Y, Cb2Z, wy, by, wz, bz, out);
}

// Round 11
// 1100.842 us; speedup vs baseline: 1.0314x; 1.0314x over previous
//
#include <hip/hip_runtime.h>

#define DEV static __device__ __forceinline__

typedef float f32x4 __attribute__((ext_vector_type(4)));
typedef __bf16 bf16x8 __attribute__((ext_vector_type(8)));
typedef unsigned int u32x4 __attribute__((ext_vector_type(4)));
typedef unsigned int u32x2 __attribute__((ext_vector_type(2)));
typedef unsigned short u16x8 __attribute__((ext_vector_type(8)));

#define NNODE 32768
#define NEDGE 393216
#define EPAD (NEDGE + 16 * NNODE)

DEV unsigned short f2bf(float f) {
    unsigned int u = __builtin_bit_cast(unsigned int, f);
    u += 0x7FFFu + ((u >> 16) & 1u);
    return (unsigned short)(u >> 16);
}
DEV float bf2f(unsigned int b) {
    unsigned int u = b << 16;
    return __builtin_bit_cast(float, u);
}
DEV unsigned int pk2(float a, float b) {
    return (unsigned int)f2bf(a) | ((unsigned int)f2bf(b) << 16);
}
DEV float sigf(float x) { return 1.f / (1.f + __expf(-x)); }

// async global->LDS, 16B per lane; LDS dest = wave-uniform base + lane*16
DEV void gld16(const void* g, void* l) {
    __builtin_amdgcn_global_load_lds(
        (const __attribute__((address_space(1))) void*)(g),
        (__attribute__((address_space(3))) void*)(l),
        16, 0, 0);
}

// ---------------- setup (init + weight packing + CSR pad/count, ONE launch) ---
// blocks [0, NNODE+8): state/feat init + Hmsg zero row.
// blocks [NNODE+8, NNODE+8+6404): weight packing (4 ranges).
// blocks [NNODE+8+6404, +EPAD/256): edat dummy-pad + degree count (cnt zeroed).
__global__ __launch_bounds__(256) void setup_k(
    const float* __restrict__ feat,
    unsigned short* __restrict__ hb0, unsigned short* __restrict__ hb1,
    unsigned short* __restrict__ fb, unsigned short* __restrict__ HmsgZ,
    const float* __restrict__ Wm,
    const float* __restrict__ Wi, const float* __restrict__ Wh,
    const float* __restrict__ bi, const float* __restrict__ bh,
    const float* __restrict__ c1w, const float* __restrict__ c2w,
    const float* __restrict__ cc1w, const float* __restrict__ cc2w,
    unsigned short* __restrict__ WT, unsigned short* __restrict__ B2T,
    float* __restrict__ b2,
    unsigned short* __restrict__ BTY, unsigned short* __restrict__ BT2,
    unsigned short* __restrict__ BTZ, unsigned short* __restrict__ BTc2,
    const int* __restrict__ dstv, int* __restrict__ cnt, int* __restrict__ edat)
{
    int blk = blockIdx.x;
    if (blk < NNODE + 8) {
        int idx = blk * 256 + threadIdx.x;
        int r = idx >> 8, c = idx & 255;
        float f = 0.f;
        if (r < NNODE && c < 128) f = feat[(size_t)r * 128 + c];
        unsigned short v = f2bf(f);
        hb0[(size_t)r * 256 + c] = v;
        hb1[(size_t)r * 256 + c] = v;
        if (c < 128) fb[(size_t)r * 128 + c] = v;
        if (r >= NNODE && r < NNODE + 4)
            HmsgZ[(size_t)(r - NNODE) * 256 + c] = 0;
        return;
    }
    if (blk >= NNODE + 8 + 6404) {                          // CSR pad + count
        int e = (blk - (NNODE + 8 + 6404)) * 256 + threadIdx.x;
        edat[e] = NNODE;
        if (e < NEDGE) atomicAdd(&cnt[dstv[e]], 1);
        return;
    }
    int gid = (blk - (NNODE + 8)) * 256 + threadIdx.x;
    if (gid < 262144) {                                     // WT
        int idx = gid;
        int j = idx >> 8, d = idx & 255;
        int t = j >> 8, o = j & 255;
        WT[idx] = f2bf(Wm[t * 65536 + d * 256 + o]);
    } else if (gid < 786432) {                              // B2T
        int idx = gid - 262144;
        int j = idx >> 9, k = idx & 511;
        int band = j >> 6, g = (j >> 4) & 3, ch = (band << 4) + (j & 15);
        float v = 0.f;
        if (g == 0) v = (k < 256) ? Wi[k * 768 + ch] : Wh[(k - 256) * 768 + ch];
        else if (g == 1) v = (k < 256) ? Wi[k * 768 + 256 + ch] : Wh[(k - 256) * 768 + 256 + ch];
        else if (g == 2) { if (k < 256) v = Wi[k * 768 + 512 + ch]; }
        else { if (k >= 256) v = Wh[(k - 256) * 768 + 512 + ch]; }
        B2T[idx] = f2bf(v);
    } else if (gid < 787456) {                              // b2
        int j = gid - 786432;
        int band = j >> 6, g = (j >> 4) & 3, ch = (band << 4) + (j & 15);
        float v;
        if (g == 0) v = bi[ch] + bh[ch];
        else if (g == 1) v = bi[256 + ch] + bh[256 + ch];
        else if (g == 2) v = bi[512 + ch];
        else v = bh[512 + ch];
        b2[j] = v;
    } else {                                                // conv packs
        int idx = gid - 787456;
        if (idx < 196608) {                                 // BTY
            int o = idx / 768, kk = idx - o * 768, k = kk >> 8, c = kk & 255;
            BTY[idx] = f2bf(c1w[o * 768 + c * 3 + k]);
        } else if (idx < 262144) {                          // BT2 [o][c]
            int r = idx - 196608, o = r >> 8, c = r & 255;
            BT2[r] = f2bf(c2w[o * 256 + c]);
        } else if (idx < 704512) {                          // BTZ
            int jx = idx - 262144, o = jx / 1152, kk = jx - o * 1152;
            float v;
            if (kk < 768) { int k = kk >> 8, c = kk & 255; v = cc1w[o * 1152 + c * 3 + k]; }
            else { int r = kk - 768, kf = r >> 7, cf = r & 127; v = cc1w[o * 1152 + (256 + cf) * 3 + kf]; }
            BTZ[jx] = f2bf(v);
        } else {                                            // BTc2 [o][c]
            int r = idx - 704512, o = r / 384, c = r - o * 384;
            BTc2[r] = f2bf(cc2w[o * 384 + c]);
        }
    }
}

// ---------------- CSR build (segments padded to multiple of 16) ----------------

// shfl-based hierarchical scan over PADDED counts ((cnt+15)&~15):
// per-wave inclusive scan -> 16 wave-sums scanned by wave 0 -> offset add.
// 2 barriers (was 20). Block offsets applied at READ time via boff.
__global__ __launch_bounds__(1024) void scan1_k(
    const int* __restrict__ cnt, int* __restrict__ rp, int* __restrict__ bsum)
{
    __shared__ int wsum[16];
    __shared__ int woff[16];
    int b = blockIdx.x, tid = threadIdx.x;
    int wave = tid >> 6, lane = tid & 63;
    int n = (b << 10) + tid;
    int v = (cnt[n] + 15) & ~15;            // padded segment length
    int s = v;
    #pragma unroll
    for (int off = 1; off < 64; off <<= 1) {
        int x = __shfl_up(s, off, 64);
        if (lane >= off) s += x;
    }
    if (lane == 63) wsum[wave] = s;
    __syncthreads();
    if (wave == 0) {
        int t = (lane < 16) ? wsum[lane] : 0;
        int ss = t;
        #pragma unroll
        for (int off = 1; off < 16; off <<= 1) {
            int x = __shfl_up(ss, off, 64);
            if (lane >= off) ss += x;
        }
        if (lane < 16) woff[lane] = ss - t; // exclusive wave offset
        if (lane == 15) bsum[b] = ss;       // block total
    }
    __syncthreads();
    rp[n] = s - v + woff[wave];             // local exclusive
}

__global__ __launch_bounds__(64) void scan2_k(
    const int* __restrict__ bsum, int* __restrict__ boff, int* __restrict__ rp)
{
    int lane = threadIdx.x;
    int v = (lane < 32) ? bsum[lane] : 0;
    int s = v;
    #pragma unroll
    for (int off = 1; off < 32; off <<= 1) {
        int x = __shfl_up(s, off, 64);
        if (lane >= off) s += x;
    }
    if (lane < 32) boff[lane] = s - v;      // exclusive block offset
    if (lane == 32) boff[32] = 0;           // sentinel for n+1 == NNODE
    if (lane == 31) rp[NNODE] = s;          // grand total (padded, full value)
}

__global__ __launch_bounds__(256) void fill_k(
    const int* __restrict__ src, const int* __restrict__ dst,
    const int* __restrict__ et, const int* __restrict__ rp,
    const int* __restrict__ boff,
    int* __restrict__ pos, int* __restrict__ edat)
{
    int e = blockIdx.x * 256 + threadIdx.x;
    int d = dst[e];
    int p = atomicAdd(&pos[d], 1);
    edat[rp[d] + boff[d >> 10] + p] = src[e] | (et[e] << 20);
}

// ---------------- per-step kernels ----------------

// one wave per node: gather Hmsg[src, et*256 .. +256] rows, sum fp32 -> Aonly.
// 16B/lane loads (32 lanes span a row), 2 edges in flight across lane halves,
// segments padded to x16 (dummy -> zero row). shfl_xor(32) combines halves.
// NO XCD swizzle: Hmsg (64 MB) is LLC-resident; chunked mapping thrashed L2
// (R10: +4.6 us/step). Default scattered mapping is faster.
__global__ __launch_bounds__(256) void agg2_k(
    const int* __restrict__ rp, const int* __restrict__ boff,
    const int* __restrict__ edat,
    const unsigned short* __restrict__ Hmsg, unsigned short* __restrict__ Aonly)
{
    int wave = threadIdx.x >> 6, lane = threadIdx.x & 63;
    int n = (blockIdx.x << 2) + wave;
    int e0 = rp[n] + boff[n >> 10];
    int e1 = rp[n + 1] + boff[(n + 1) >> 10];
    int half = lane >> 5, lc = lane & 31;
    float a0 = 0.f, a1 = 0.f, a2 = 0.f, a3 = 0.f;
    float a4 = 0.f, a5 = 0.f, a6 = 0.f, a7 = 0.f;
    const unsigned short* hc = Hmsg + (lc << 3);
    for (int e = e0; e < e1; e += 16) {
        u32x4 v[8];
        #pragma unroll
        for (int q = 0; q < 8; q++) {
            int d = edat[e + (q << 1) + half];
            v[q] = *(const u32x4*)(hc + ((size_t)(d & 0xFFFFF) << 10) + ((d >> 20) << 8));
        }
        #pragma unroll
        for (int q = 0; q < 8; q++) {
            a0 += bf2f(v[q].x & 0xFFFFu); a1 += bf2f(v[q].x >> 16);
            a2 += bf2f(v[q].y & 0xFFFFu); a3 += bf2f(v[q].y >> 16);
            a4 += bf2f(v[q].z & 0xFFFFu); a5 += bf2f(v[q].z >> 16);
            a6 += bf2f(v[q].w & 0xFFFFu); a7 += bf2f(v[q].w >> 16);
        }
    }
    a0 += __shfl_xor(a0, 32, 64); a1 += __shfl_xor(a1, 32, 64);
    a2 += __shfl_xor(a2, 32, 64); a3 += __shfl_xor(a3, 32, 64);
    a4 += __shfl_xor(a4, 32, 64); a5 += __shfl_xor(a5, 32, 64);
    a6 += __shfl_xor(a6, 32, 64); a7 += __shfl_xor(a7, 32, 64);
    if (half == 0) {
        u32x4 p;
        p.x = pk2(a0, a1); p.y = pk2(a2, a3);
        p.z = pk2(a4, a5); p.w = pk2(a6, a7);
        *(u32x4*)(Aonly + (size_t)n * 256 + (lc << 3)) = p;
    }
}

// ---- BK=64 staging helpers, bank-conflict-free XOR swizzle.
#define STAGE_COORDS                                            \
    int srow[4], scb[4], soff[4];                               \
    _Pragma("unroll")                                           \
    for (int p = 0; p < 4; p++) {                               \
        int c = wave + p * 4;                                   \
        int half = c >> 3, cc = c & 7;                          \
        srow[p] = cc * 16 + (lane >> 2);                        \
        scb[p] = (((lane & 3) ^ ((lane >> 3) & 3)) + half * 4) * 8; \
        soff[p] = half * 4096 + cc * 512;                       \
    }

// MFMA over one 64-K LDS tile pair (two 32-K halves), swapped operands,
// swizzled fragment reads
#define MFMA64(AS, BS)                                                        \
    _Pragma("unroll")                                                         \
    for (int h = 0; h < 2; h++) {                                             \
        bf16x8 af[4], bfr[4];                                                 \
        _Pragma("unroll")                                                     \
        for (int i = 0; i < 4; i++)                                           \
            af[i] = *(const bf16x8*)(&(AS)[h * 4096 + (qm + i * 16 + fm) * 32 + fksw * 8]); \
        _Pragma("unroll")                                                     \
        for (int i = 0; i < 4; i++)                                           \
            bfr[i] = *(const bf16x8*)(&(BS)[h * 4096 + (qn + i * 16 + fm) * 32 + fksw * 8]); \
        _Pragma("unroll")                                                     \
        for (int i = 0; i < 4; i++)                                           \
            _Pragma("unroll")                                                 \
            for (int j = 0; j < 4; j++)                                       \
                acc[i][j] = __builtin_amdgcn_mfma_f32_16x16x32_bf16(bfr[j], af[i], acc[i][j], 0, 0, 0); \
    }

// gate-skip variant: skip j-fragment SK (its B2T block is exactly zero)
#define MFMA64G(AS, BS, SK)                                                   \
    _Pragma("unroll")                                                         \
    for (int h = 0; h < 2; h++) {                                             \
        bf16x8 af[4], bfr[4];                                                 \
        _Pragma("unroll")                                                     \
        for (int i = 0; i < 4; i++)                                           \
            af[i] = *(const bf16x8*)(&(AS)[h * 4096 + (qm + i * 16 + fm) * 32 + fksw * 8]); \
        _Pragma("unroll")                                                     \
        for (int j = 0; j < 4; j++) {                                         \
            if (j == (SK)) continue;                                          \
            bfr[j] = *(const bf16x8*)(&(BS)[h * 4096 + (qn + j * 16 + fm) * 32 + fksw * 8]); \
        }                                                                     \
        _Pragma("unroll")                                                     \
        for (int i = 0; i < 4; i++)                                           \
            _Pragma("unroll")                                                 \
            for (int j = 0; j < 4; j++) {                                     \
                if (j == (SK)) continue;                                      \
                acc[i][j] = __builtin_amdgcn_mfma_f32_16x16x32_bf16(bfr[j], af[i], acc[i][j], 0, 0, 0); \
            }                                                                 \
    }

// Hmsg GEMM: C[Nn,1024] = h @ WT^T + bmsg. 128x128 tile, BK=64, K=NT*64,
// 2-phase dbuf staging, XCD swizzle. NT=2 at step 0 (h cols 128..255 zero).
template<int NT>
__global__ __launch_bounds__(256) void gemm_hmsg(
    const unsigned short* __restrict__ A,
    const unsigned short* __restrict__ Bt,
    unsigned short* __restrict__ Cb,
    const float* __restrict__ bias)
{
    __shared__ __align__(16) unsigned short As0[128 * 64];
    __shared__ __align__(16) unsigned short As1[128 * 64];
    __shared__ __align__(16) unsigned short Bs0[128 * 64];
    __shared__ __align__(16) unsigned short Bs1[128 * 64];
    const int tid = threadIdx.x;
    int id = blockIdx.x;                        // 2048
    { int per = gridDim.x >> 3; id = (id & 7) * per + (id >> 3); }
    const int bm = id >> 3, bn = id & 7;
    const int wave = tid >> 6, lane = tid & 63;
    const unsigned short* Ag = A + (size_t)(bm * 128) * 256;
    const unsigned short* Bg = Bt + (size_t)(bn * 128) * 256;
    const int qm = (wave & 1) << 6, qn = (wave >> 1) << 6;
    const int fm = lane & 15, fkv = lane >> 4;
    const int fksw = fkv ^ ((fm >> 1) & 3);
    STAGE_COORDS

    auto stageA = [&](int kb, unsigned short* dst) {
        #pragma unroll
        for (int p = 0; p < 4; p++)
            gld16(Ag + (size_t)srow[p] * 256 + kb + scb[p], dst + soff[p]);
    };
    auto stageB = [&](int kb, unsigned short* dst) {
        #pragma unroll
        for (int p = 0; p < 4; p++)
            gld16(Bg + (size_t)srow[p] * 256 + kb + scb[p], dst + soff[p]);
    };

    f32x4 acc[4][4] = {};

    stageA(0, As0); stageB(0, Bs0);
    __syncthreads();
    unsigned short *Ac = As0, *An = As1, *Bc = Bs0, *Bn = Bs1;
    #pragma unroll
    for (int kb = 0; kb < NT * 64; kb += 64) {
        if (kb + 64 < NT * 64) { stageA(kb + 64, An); stageB(kb + 64, Bn); }
        MFMA64(Ac, Bc)
        __syncthreads();
        { auto t = Ac; Ac = An; An = t; }
        { auto t = Bc; Bc = Bn; Bn = t; }
    }

    const int m0 = bm * 128 + qm + fm;
    const int n0 = bn * 128 + qn + (fkv << 2);
    #pragma unroll
    for (int i = 0; i < 4; i++) {
        int row = m0 + i * 16;
        #pragma unroll
        for (int j = 0; j < 4; j++) {
            int col = n0 + j * 16;
            float4 bv = *(const float4*)(bias + col);
            u32x2 p;
            p.x = pk2(acc[i][j][0] + bv.x, acc[i][j][1] + bv.y);
            p.y = pk2(acc[i][j][2] + bv.z, acc[i][j][3] + bv.w);
            *(u32x2*)(Cb + (size_t)row * 1024 + col) = p;
        }
    }
}

// merged conv1 GEMMs (Y then Z) in ONE launch; blocks [0,512) = Y
// (N=256,K=768), [512,1280) = Z (N=384,K=1152). Per-segment XCD swizzle.
// K layout: kb<768 -> h chunks (lda 256, shift kb>>8), kb>=768 -> f chunks
// (lda 128, shift (kb-768)>>7). BK=64. 2-phase dbuf staging.
__global__ __launch_bounds__(256) void gemm_conv2(
    const unsigned short* __restrict__ Ah,
    const unsigned short* __restrict__ Af,
    const unsigned short* __restrict__ BtY,
    const unsigned short* __restrict__ BtZ,
    unsigned short* __restrict__ CbYo,
    unsigned short* __restrict__ CbZo,
    const float* __restrict__ biasY,
    const float* __restrict__ biasZ)
{
    __shared__ __align__(16) unsigned short As0[128 * 64];
    __shared__ __align__(16) unsigned short As1[128 * 64];
    __shared__ __align__(16) unsigned short Bs0[128 * 64];
    __shared__ __align__(16) unsigned short Bs1[128 * 64];
    const int tid = threadIdx.x;
    const unsigned short* Bt; unsigned short* Cb;
    const float* bias; int N, K, ldcb, id;
    if (blockIdx.x < 512) {
        id = blockIdx.x;
        { int per = 512 >> 3; id = (id & 7) * per + (id >> 3); }
        Bt = BtY; Cb = CbYo; bias = biasY; N = 256; K = 768; ldcb = 256;
    } else {
        id = blockIdx.x - 512;
        { int per = 768 >> 3; id = (id & 7) * per + (id >> 3); }
        Bt = BtZ; Cb = CbZo; bias = biasZ; N = 384; K = 1152; ldcb = 384;
    }
    const int nb = N >> 7;
    const int bm = id / nb, bn = id - bm * nb;
    const int wave = tid >> 6, lane = tid & 63;
    const unsigned short* Bg = Bt + (size_t)(bn * 128) * K;
    const int qm = (wave & 1) << 6, qn = (wave >> 1) << 6;
    const int fm = lane & 15, fkv = lane >> 4;
    const int fksw = fkv ^ ((fm >> 1) & 3);
    STAGE_COORDS

    auto stageA = [&](int kb, unsigned short* dst) {
        const unsigned short* base; int ldA, col, shift;
        if (kb < 768) { base = Ah; ldA = 256; shift = kb >> 8; col = kb & 255; }
        else { int r = kb - 768; base = Af; ldA = 128; shift = r >> 7; col = r & 127; }
        const unsigned short* Ag = base + (size_t)(bm * 128 + shift) * ldA + col;
        #pragma unroll
        for (int p = 0; p < 4; p++)
            gld16(Ag + (size_t)srow[p] * ldA + scb[p], dst + soff[p]);
    };
    auto stageB = [&](int kb, unsigned short* dst) {
        #pragma unroll
        for (int p = 0; p < 4; p++)
            gld16(Bg + (size_t)srow[p] * K + kb + scb[p], dst + soff[p]);
    };

    f32x4 acc[4][4] = {};

    stageA(0, As0); stageB(0, Bs0);
    __syncthreads();
    unsigned short *Ac = As0, *An = As1, *Bc = Bs0, *Bn = Bs1;
    for (int kb = 0; kb < K; kb += 64) {
        if (kb + 64 < K) { stageA(kb + 64, An); stageB(kb + 64, Bn); }
        MFMA64(Ac, Bc)
        __syncthreads();
        { auto t = Ac; Ac = An; An = t; }
        { auto t = Bc; Bc = Bn; Bn = t; }
    }

    const int m0 = bm * 128 + qm + fm;
    const int n0 = bn * 128 + qn + (fkv << 2);
    #pragma unroll
    for (int i = 0; i < 4; i++) {
        int row = m0 + i * 16;
        #pragma unroll
        for (int j = 0; j < 4; j++) {
            int col = n0 + j * 16;
            float4 bv = *(const float4*)(bias + col);
            float v0 = fmaxf(acc[i][j][0] + bv.x, 0.f);
            float v1 = fmaxf(acc[i][j][1] + bv.y, 0.f);
            float v2 = fmaxf(acc[i][j][2] + bv.z, 0.f);
            float v3 = fmaxf(acc[i][j][3] + bv.w, 0.f);
            u32x2 p; p.x = pk2(v0, v1); p.y = pk2(v2, v3);
            *(u32x2*)(Cb + (size_t)row * ldcb + col) = p;
        }
    }
}

// merged conv2 GEMMs with FUSED maxpool(win3,stride2) on A, ONE launch:
// blocks [0,252) = Y (C=256), [252,630) = Z (C=384). A[row] = max of 3
// consecutive-l rows of CbX (post-relu bf16 -> u16 max is exact).
// Reg-staged A (T14 split: loads before MFMA, max+ds_write after); B gld16.
__global__ __launch_bounds__(256) void gemm_pool2(
    const unsigned short* __restrict__ CbYi,
    const unsigned short* __restrict__ CbZi,
    const unsigned short* __restrict__ BtY,
    const unsigned short* __restrict__ BtZ,
    unsigned short* __restrict__ Cb2Yo,
    unsigned short* __restrict__ Cb2Zo,
    const float* __restrict__ biasY,
    const float* __restrict__ biasZ)
{
    __shared__ __align__(16) unsigned short As0[128 * 64];
    __shared__ __align__(16) unsigned short As1[128 * 64];
    __shared__ __align__(16) unsigned short Bs0[128 * 64];
    __shared__ __align__(16) unsigned short Bs1[128 * 64];
    const int tid = threadIdx.x;
    const unsigned short* CbX; const unsigned short* Bt; unsigned short* Cb;
    const float* bias; int N, K, id;
    if (blockIdx.x < 252) {
        id = blockIdx.x;
        CbX = CbYi; Bt = BtY; Cb = Cb2Yo; bias = biasY; N = 256; K = 256;
    } else {
        id = blockIdx.x - 252;
        CbX = CbZi; Bt = BtZ; Cb = Cb2Zo; bias = biasZ; N = 384; K = 384;
    }
    const int ldin = K, ldcb = N;
    const int nb = N >> 7;
    const int bm = id / nb, bn = id - bm * nb;
    const int wave = tid >> 6, lane = tid & 63;
    const unsigned short* Bg = Bt + (size_t)(bn * 128) * K;
    const int qm = (wave & 1) << 6, qn = (wave >> 1) << 6;
    const int fm = lane & 15, fkv = lane >> 4;
    const int fksw = fkv ^ ((fm >> 1) & 3);
    STAGE_COORDS

    // pooled row -> source row0 in CbX (graph b: 126 pooled rows, 256 src)
    int row0[4];
    #pragma unroll
    for (int p = 0; p < 4; p++) {
        int arow = bm * 128 + srow[p];
        int b = arow / 126, lp = arow - b * 126;
        row0[p] = b * 256 + 2 * lp;
    }

    u16x8 va[4][3];
    auto loadA3 = [&](int kb) {
        #pragma unroll
        for (int p = 0; p < 4; p++) {
            const unsigned short* s = CbX + (size_t)row0[p] * ldin + kb + scb[p];
            va[p][0] = *(const u16x8*)s;
            va[p][1] = *(const u16x8*)(s + ldin);
            va[p][2] = *(const u16x8*)(s + 2 * ldin);
        }
    };
    auto writeA = [&](unsigned short* dst) {
        #pragma unroll
        for (int p = 0; p < 4; p++) {
            u16x8 m = __builtin_elementwise_max(
                __builtin_elementwise_max(va[p][0], va[p][1]), va[p][2]);
            *(u16x8*)(dst + soff[p] + lane * 8) = m;   // same layout as gld16
        }
    };
    auto stageB = [&](int kb, unsigned short* dst) {
        #pragma unroll
        for (int p = 0; p < 4; p++)
            gld16(Bg + (size_t)srow[p] * K + kb + scb[p], dst + soff[p]);
    };

    f32x4 acc[4][4] = {};

    loadA3(0); writeA(As0); stageB(0, Bs0);
    __syncthreads();
    unsigned short *Ac = As0, *An = As1, *Bc = Bs0, *Bn = Bs1;
    for (int kb = 0; kb < K; kb += 64) {
        bool more = (kb + 64 < K);
        if (more) { loadA3(kb + 64); stageB(kb + 64, Bn); }
        MFMA64(Ac, Bc)
        if (more) writeA(An);       // loads' latency hidden under the MFMAs
        __syncthreads();
        { auto t = Ac; Ac = An; An = t; }
        { auto t = Bc; Bc = Bn; Bn = t; }
    }

    const int m0 = bm * 128 + qm + fm;
    const int n0 = bn * 128 + qn + (fkv << 2);
    #pragma unroll
    for (int i = 0; i < 4; i++) {
        int row = m0 + i * 16;
        #pragma unroll
        for (int j = 0; j < 4; j++) {
            int col = n0 + j * 16;
            float4 bv = *(const float4*)(bias + col);
            float v0 = fmaxf(acc[i][j][0] + bv.x, 0.f);
            float v1 = fmaxf(acc[i][j][1] + bv.y, 0.f);
            float v2 = fmaxf(acc[i][j][2] + bv.z, 0.f);
            float v3 = fmaxf(acc[i][j][3] + bv.w, 0.f);
            u32x2 p; p.x = pk2(v0, v1); p.y = pk2(v2, v3);
            *(u32x2*)(Cb + (size_t)row * ldcb + col) = p;
        }
    }
}

// GRU GEMM + fused gate epilogue (swapped MFMA, BK=64, K=NT*64, 2-phase
// dbuf staging, gate-skip). NT=6 at step 0 (h cols 128..255 exactly zero).
template<int NT>
__global__ __launch_bounds__(256) void gemm_gru(
    const unsigned short* __restrict__ Aonly,
    const unsigned short* __restrict__ hbc,
    const unsigned short* __restrict__ Bt,
    const float* __restrict__ b2p,
    unsigned short* __restrict__ hbn)
{
    __shared__ __align__(16) unsigned short As0[128 * 64];
    __shared__ __align__(16) unsigned short As1[128 * 64];
    __shared__ __align__(16) unsigned short Bs0[128 * 64];
    __shared__ __align__(16) unsigned short Bs1[128 * 64];
    const int tid = threadIdx.x;
    int id = blockIdx.x;                        // 2048
    { int per = gridDim.x >> 3; id = (id & 7) * per + (id >> 3); }
    const int bm = id >> 3;
    const int bn = id & 7;
    const int wave = tid >> 6, lane = tid & 63;
    const unsigned short* Bg = Bt + (size_t)(bn * 128) * 512;
    const int qm = (wave & 1) << 6, qn = (wave >> 1) << 6;
    const int fm = lane & 15, fkv = lane >> 4;
    const int fksw = fkv ^ ((fm >> 1) & 3);
    STAGE_COORDS

    auto stageA = [&](int kb, unsigned short* dst) {
        const unsigned short* base = (kb < 256) ? Aonly : hbc;
        const unsigned short* Ag = base + (size_t)(bm * 128) * 256 + (kb & 255);
        #pragma unroll
        for (int p = 0; p < 4; p++)
            gld16(Ag + (size_t)srow[p] * 256 + scb[p], dst + soff[p]);
    };
    auto stageB = [&](int kb, unsigned short* dst) {
        #pragma unroll
        for (int p = 0; p < 4; p++)
            gld16(Bg + (size_t)srow[p] * 512 + kb + scb[p], dst + soff[p]);
    };

    f32x4 acc[4][4] = {};

    stageA(0, As0); stageB(0, Bs0);
    __syncthreads();
    unsigned short *Ac = As0, *An = As1, *Bc = Bs0, *Bn = Bs1;
    #pragma unroll
    for (int kb = 0; kb < NT * 64; kb += 64) {
        if (kb + 64 < NT * 64) { stageA(kb + 64, An); stageB(kb + 64, Bn); }
        if (kb < 256) { MFMA64G(Ac, Bc, 3) }    // hg block zero for k<256
        else          { MFMA64G(Ac, Bc, 2) }    // ig block zero for k>=256
        __syncthreads();
        { auto t = Ac; Ac = An; An = t; }
        { auto t = Bc; Bc = Bn; Bn = t; }
    }

    // fused GRU gate epilogue (bf16 state, 8B vector I/O)
    const int band = (bn << 1) + (qn >> 6);
    const int chb = (band << 4) + (fkv << 2);
    const float4 brv = *(const float4*)(b2p + (band << 6) + 0  + (fkv << 2));
    const float4 bzv = *(const float4*)(b2p + (band << 6) + 16 + (fkv << 2));
    const float4 bgv = *(const float4*)(b2p + (band << 6) + 32 + (fkv << 2));
    const float4 bhv = *(const float4*)(b2p + (band << 6) + 48 + (fkv << 2));
    const float br_[4] = {brv.x, brv.y, brv.z, brv.w};
    const float bz_[4] = {bzv.x, bzv.y, bzv.z, bzv.w};
    const float bg_[4] = {bgv.x, bgv.y, bgv.z, bgv.w};
    const float bh_[4] = {bhv.x, bhv.y, bhv.z, bhv.w};
    const int m0 = bm * 128 + qm + fm;
    #pragma unroll
    for (int i = 0; i < 4; i++) {
        int row = m0 + i * 16;
        u32x2 hv = *(const u32x2*)(hbc + (size_t)row * 256 + chb);
        float hp[4] = {bf2f(hv.x & 0xFFFFu), bf2f(hv.x >> 16),
                       bf2f(hv.y & 0xFFFFu), bf2f(hv.y >> 16)};
        float hn[4];
        #pragma unroll
        for (int r = 0; r < 4; r++) {
            float rg = sigf(acc[i][0][r] + br_[r]);
            float zz = sigf(acc[i][1][r] + bz_[r]);
            float pre = acc[i][2][r] + bg_[r] + rg * (acc[i][3][r] + bh_[r]);
            pre = fminf(fmaxf(pre, -15.f), 15.f);
            float t = __expf(2.f * pre);
            float gq = (t - 1.f) / (t + 1.f);
            hn[r] = (1.f - zz) * gq + zz * hp[r];
        }
        u32x2 p; p.x = pk2(hn[0], hn[1]); p.y = pk2(hn[2], hn[3]);
        *(u32x2*)(hbn + (size_t)row * 256 + chb) = p;
    }
}

// fused pool2(win=2) + dot + mean + sigmoid. 256 threads/graph:
// 4 waves split the 63 l-positions; lanes split channels; shfl reduce.
__global__ __launch_bounds__(256) void final_k(
    const unsigned short* __restrict__ CY, const unsigned short* __restrict__ CZ,
    const float* __restrict__ wy, const float* __restrict__ by,
    const float* __restrict__ wz, const float* __restrict__ bz,
    float* __restrict__ out)
{
    __shared__ float ws[4];
    int b = blockIdx.x, tid = threadIdx.x;
    int wave = tid >> 6, lane = tid & 63;
    float wyv[4], wzv[6];
    #pragma unroll
    for (int j = 0; j < 4; j++) wyv[j] = wy[lane * 4 + j];
    #pragma unroll
    for (int j = 0; j < 6; j++) wzv[j] = wz[lane * 6 + j];
    const float byv = by[0], bzv = bz[0];
    float acc = 0.f;
    for (int l = wave; l < 63; l += 4) {
        const unsigned short* y0 = CY + (size_t)(b * 126 + 2 * l) * 256 + lane * 4;
        const unsigned short* y1 = y0 + 256;
        u32x2 u0 = *(const u32x2*)y0, u1 = *(const u32x2*)y1;
        float py =
            fmaxf(bf2f(u0.x & 0xFFFFu), bf2f(u1.x & 0xFFFFu)) * wyv[0] +
            fmaxf(bf2f(u0.x >> 16),     bf2f(u1.x >> 16))     * wyv[1] +
            fmaxf(bf2f(u0.y & 0xFFFFu), bf2f(u1.y & 0xFFFFu)) * wyv[2] +
            fmaxf(bf2f(u0.y >> 16),     bf2f(u1.y >> 16))     * wyv[3];
        const unsigned short* z0 = CZ + (size_t)(b * 126 + 2 * l) * 384 + lane * 6;
        const unsigned short* z1 = z0 + 384;
        float pz = 0.f;
        #pragma unroll
        for (int j = 0; j < 6; j++)
            pz += fmaxf(bf2f(z0[j]), bf2f(z1[j])) * wzv[j];
        #pragma unroll
        for (int off = 32; off > 0; off >>= 1) {
            py += __shfl_down(py, off, 64);
            pz += __shfl_down(pz, off, 64);
        }
        if (lane == 0) acc += (py + byv) * (pz + bzv);
    }
    if (lane == 0) ws[wave] = acc;
    __syncthreads();
    if (tid == 0)
        out[b] = sigf((ws[0] + ws[1] + ws[2] + ws[3]) * (1.f / 63.f));
}

// ---------------- launch ----------------

extern "C" void kernel_launch(void* const* d_in, const int* in_sizes, int n_in,
                              void* d_out, int out_size, void* d_ws, size_t ws_size,
                              hipStream_t stream)
{
    const float* feat = (const float*)d_in[0];
    const int* src = (const int*)d_in[1];
    const int* dst = (const int*)d_in[2];
    const int* et  = (const int*)d_in[3];
    const float* Wm  = (const float*)d_in[4];
    const float* bm  = (const float*)d_in[5];
    const float* Wi  = (const float*)d_in[6];
    const float* Wh  = (const float*)d_in[7];
    const float* bi  = (const float*)d_in[8];
    const float* bh  = (const float*)d_in[9];
    const float* c1w = (const float*)d_in[10];
    const float* c1b = (const float*)d_in[11];
    const float* c2w = (const float*)d_in[12];
    const float* c2b = (const float*)d_in[13];
    const float* cc1w = (const float*)d_in[14];
    const float* cc1b = (const float*)d_in[15];
    const float* cc2w = (const float*)d_in[16];
    const float* cc2b = (const float*)d_in[17];
    const float* wy = (const float*)d_in[18];
    const float* by = (const float*)d_in[19];
    const float* wz = (const float*)d_in[20];
    const float* bz = (const float*)d_in[21];
    float* out = (float*)d_out;

    char* w = (char*)d_ws;
    size_t off = 0;
    auto alloc = [&](size_t bytes) -> char* {
        char* p = w + off; off += (bytes + 255) & ~(size_t)255; return p;
    };
    unsigned short* hb0 = (unsigned short*)alloc((size_t)(NNODE + 8) * 256 * 2);
    unsigned short* hb1 = (unsigned short*)alloc((size_t)(NNODE + 8) * 256 * 2);
    unsigned short* fb  = (unsigned short*)alloc((size_t)(NNODE + 8) * 128 * 2);
    unsigned short* Aonly = (unsigned short*)alloc((size_t)NNODE * 256 * 2);
    char* R = alloc((size_t)(NNODE + 1) * 1024 * 2);    // Hmsg(+zero row) / conv1-out
    unsigned short* Hmsg = (unsigned short*)R;          // [Nn+1,1024] bf16
    unsigned short* CbY  = (unsigned short*)R;          // [Nn,256] bf16 (conv1 Y)
    unsigned short* CbZ  = (unsigned short*)(R + (size_t)NNODE * 256 * 2); // [Nn,384]
    unsigned short* Cb2Y = (unsigned short*)alloc((size_t)16128 * 256 * 2);
    unsigned short* Cb2Z = (unsigned short*)alloc((size_t)16128 * 384 * 2);
    unsigned short* WT   = (unsigned short*)alloc(1024 * 256 * 2);
    unsigned short* B2T  = (unsigned short*)alloc(1024 * 512 * 2);
    float* b2            = (float*)alloc(1024 * 4);
    unsigned short* BTY  = (unsigned short*)alloc(256 * 768 * 2);
    unsigned short* BT2  = (unsigned short*)alloc(256 * 256 * 2);
    unsigned short* BTZ  = (unsigned short*)alloc(384 * 1152 * 2);
    unsigned short* BTc2 = (unsigned short*)alloc(384 * 384 * 2);
    int* rp     = (int*)alloc((NNODE + 1) * 4);
    int* pos    = (int*)alloc(NNODE * 4);
    int* cnt    = (int*)alloc(NNODE * 4);
    int* bsum   = (int*)alloc(32 * 4);
    int* boff   = (int*)alloc(33 * 4);
    int* edat   = (int*)alloc((size_t)EPAD * 4);

    // setup: memset first (cnt zeroed before setup_k's count range runs)
    hipMemsetAsync(pos, 0, 2 * NNODE * 4, stream);      // pos+cnt contiguous
    hipLaunchKernelGGL(setup_k, dim3(NNODE + 8 + 6404 + EPAD / 256), dim3(256),
                       0, stream,
                       feat, hb0, hb1, fb, Hmsg + (size_t)NNODE * 1024,
                       Wm, Wi, Wh, bi, bh, c1w, c2w, cc1w, cc2w,
                       WT, B2T, b2, BTY, BT2, BTZ, BTc2,
                       dst, cnt, edat);
    hipLaunchKernelGGL(scan1_k, dim3(32), dim3(1024), 0, stream, cnt, rp, bsum);
    hipLaunchKernelGGL(scan2_k, dim3(1), dim3(64), 0, stream, bsum, boff, rp);
    hipLaunchKernelGGL(fill_k, dim3(NEDGE / 256), dim3(256), 0, stream,
                       src, dst, et, rp, boff, pos, edat);

    // 8 GGNN steps; bf16 state double-buffered (hb0 -> hb1 -> hb0 ...)
    // per step: Hmsg = hb@WT + bm  ->  Aonly[dst] = sum Hmsg[src, et]  ->  GRU
    // step 0: h cols 128..255 are exactly zero -> half-K Hmsg, 6-tile GRU.
    unsigned short* hbuf[2] = {hb0, hb1};
    for (int step = 0; step < 8; step++) {
        unsigned short* cur = hbuf[step & 1];
        unsigned short* nxt = hbuf[(step + 1) & 1];
        if (step == 0)
            hipLaunchKernelGGL((gemm_hmsg<2>), dim3(2048), dim3(256), 0, stream,
                cur, WT, Hmsg, bm);
        else
            hipLaunchKernelGGL((gemm_hmsg<4>), dim3(2048), dim3(256), 0, stream,
                cur, WT, Hmsg, bm);
        hipLaunchKernelGGL(agg2_k, dim3(NNODE / 4), dim3(256), 0, stream,
            rp, boff, edat, Hmsg, Aonly);
        if (step == 0)
            hipLaunchKernelGGL((gemm_gru<6>), dim3(2048), dim3(256), 0, stream,
                Aonly, cur, B2T, b2, nxt);
        else
            hipLaunchKernelGGL((gemm_gru<8>), dim3(2048), dim3(256), 0, stream,
                Aonly, cur, B2T, b2, nxt);
    }
    // final state is in hb0 (after 8 flips)

    // readout: merged conv1 (Y+Z, one launch), merged pooled conv2 (Y+Z)
    hipLaunchKernelGGL(gemm_conv2, dim3(1280), dim3(256), 0, stream,
        hb0, fb, BTY, BTZ, CbY, CbZ, c1b, cc1b);
    hipLaunchKernelGGL(gemm_pool2, dim3(630), dim3(256), 0, stream,
        CbY, CbZ, BT2, BTc2, Cb2Y, Cb2Z, c2b, cc2b);

    // fused pool2 + readout heads
    hipLaunchKernelGGL(final_k, dim3(128), dim3(256), 0, stream,
        Cb2Y, Cb2Z, wy, by, wz, bz, out);
}